// Round 19
// baseline (681.320 us; speedup 1.0000x reference)
//
#include <hip/hip_runtime.h>
#include <stdint.h>
#include <math.h>

// ---------------- problem constants ----------------
constexpr int BB = 2;
constexpr int V0 = 4096;
constexpr int V1 = 1024;
constexpr int V2 = 256;
constexpr int KNN = 10;

// ---------------- host-side NumPy RNG (sub-mix + masked rejection; VERIFIED R13) ------
namespace nprng {

typedef unsigned __int128 u128;
struct PCG { u128 state, inc; uint64_t buf; bool has32; };
static const u128 PCG_MUL = (((u128)0x2360ED051FC65DA4ULL) << 64) | 0x4385DF649FCCF645ULL;

static void pcg_init(uint32_t seed, PCG& g) {
  uint32_t hc = 0x43b0d7e5u;                    // INIT_A
  auto hashm = [&](uint32_t v, uint32_t mult) -> uint32_t {
    v ^= hc; hc *= mult; v *= hc; v ^= v >> 16; return v;
  };
  auto mixf = [](uint32_t x, uint32_t y) -> uint32_t {
    uint32_t r = (uint32_t)(x * 0xca01f9ddu - y * 0x4973f715u);  // SUBTRACTION
    r ^= r >> 16; return r;
  };
  uint32_t pool[4];
  pool[0] = hashm(seed, 0x931e8875u);
  for (int i = 1; i < 4; ++i) pool[i] = hashm(0u, 0x931e8875u);
  for (int s = 0; s < 4; ++s)
    for (int d = 0; d < 4; ++d)
      if (s != d) pool[d] = mixf(pool[d], hashm(pool[s], 0x931e8875u));
  hc = 0x8b51f9ddu;                             // INIT_B
  uint32_t w[8];
  for (int i = 0; i < 8; ++i) w[i] = hashm(pool[i & 3], 0x58f38dedu);
  uint64_t q0 = ((uint64_t)w[1] << 32) | w[0];
  uint64_t q1 = ((uint64_t)w[3] << 32) | w[2];
  uint64_t q2 = ((uint64_t)w[5] << 32) | w[4];
  uint64_t q3 = ((uint64_t)w[7] << 32) | w[6];
  u128 initstate = (((u128)q0) << 64) | q1;
  u128 initseq   = (((u128)q2) << 64) | q3;
  g.inc = (initseq << 1) | 1;
  g.state = g.inc;
  g.state += initstate;
  g.state = g.state * PCG_MUL + g.inc;
  g.has32 = false; g.buf = 0;
}

static uint64_t pcg_next64(PCG& g) {
  g.state = g.state * PCG_MUL + g.inc;
  uint64_t hi = (uint64_t)(g.state >> 64), lo = (uint64_t)g.state;
  unsigned r = (unsigned)(hi >> 58);
  uint64_t x = hi ^ lo;
  return (x >> r) | (x << ((64u - r) & 63u));
}

static uint32_t pcg_next32(PCG& g) {
  if (g.has32) { g.has32 = false; return (uint32_t)g.buf; }
  uint64_t n = pcg_next64(g);
  g.has32 = true; g.buf = n >> 32;
  return (uint32_t)n;                            // low 32 first
}

static uint32_t masked32(PCG& g, uint32_t rng) { // numpy random_interval
  uint32_t mask = rng;
  mask |= mask >> 1; mask |= mask >> 2; mask |= mask >> 4;
  mask |= mask >> 8; mask |= mask >> 16;
  uint32_t v;
  while ((v = (pcg_next32(g) & mask)) > rng) {}
  return v;
}

static void permutation(uint32_t seed, int n, int* out) {
  PCG g; pcg_init(seed, g);
  for (int i = 0; i < n; ++i) out[i] = i;
  for (int i = n - 1; i > 0; --i) {
    uint32_t j = masked32(g, (uint32_t)i);
    int t = out[j]; out[j] = out[i]; out[i] = t;
  }
}

static double first_double(uint32_t seed) {
  PCG g; pcg_init(seed, g);
  return (double)(pcg_next64(g) >> 11) * (1.0 / 9007199254740992.0);
}

} // namespace nprng

// ---------------- np-f32-exact distance pieces (no FMA contraction) ----------------
__device__ inline float np_sq3(float x, float y, float z) {
  return __fadd_rn(__fadd_rn(__fmul_rn(x, x), __fmul_rn(y, y)), __fmul_rn(z, z));
}
__device__ inline float np_inner3(float ax, float ay, float az, float bx, float by, float bz) {
  return __fadd_rn(__fadd_rn(__fmul_rn(ax, bx), __fmul_rn(ay, by)), __fmul_rn(az, bz));
}

// ---------------- ws-overflow guard ----------------
__global__ void fill_kernel(float* __restrict__ out, float v, int n) {
  int i = blockIdx.x * 256 + threadIdx.x;
  if (i < n) out[i] = v;
}

// ---------------- tiny upload kernel ----------------
struct IntPack256 { int v[256]; };
__global__ void upload256_kernel(IntPack256 p, int* __restrict__ dst) {
  dst[threadIdx.x] = p.v[threadIdx.x];
}

// ---------------- normalize direction columns ----------------
__global__ void norm_dirs_kernel(const float* __restrict__ d, float* __restrict__ nd, int M) {
  int m = blockIdx.x * 256 + threadIdx.x;
  if (m >= M) return;
  float a = d[m], b = d[M + m], c = d[2 * M + m];
  float n = sqrtf((a * a + b * b) + c * c);
  n = fmaxf(n, 1e-12f);
  nd[m] = a / n; nd[M + m] = b / n; nd[2 * M + m] = c / n;
}

// ---------------- chunked knn: phase 1 — per-chunk sorted top-11 (R14 body) ----------
template<int NPTS, int CH>
__global__ __launch_bounds__(64) void knn_part_kernel(const float* __restrict__ verts,
                                                      float* __restrict__ pd,
                                                      int* __restrict__ pi) {
  constexpr int CND = NPTS / CH;
  __shared__ float sx[CND], sy[CND], sz[CND];
  const int bpb = NPTS / 64;
  const int b = blockIdx.x / bpb;
  const int q = (blockIdx.x % bpb) * 64 + threadIdx.x;
  const int ch = blockIdx.y;
  const float* vb = verts + (size_t)b * NPTS * 3;
  for (int i = threadIdx.x; i < CND; i += 64) {
    int j = ch * CND + i;
    sx[i] = vb[3 * j]; sy[i] = vb[3 * j + 1]; sz[i] = vb[3 * j + 2];
  }
  __syncthreads();
  const float px = vb[3 * q], py = vb[3 * q + 1], pz = vb[3 * q + 2];
  const float psq = np_sq3(px, py, pz);
  float bd[11]; int bi[11];
#pragma unroll
  for (int t = 0; t < 11; ++t) { bd[t] = __builtin_inff(); bi[t] = 0; }
  for (int jj = 0; jj < CND; ++jj) {
    float inner = np_inner3(px, py, pz, sx[jj], sy[jj], sz[jj]);
    float osq = np_sq3(sx[jj], sy[jj], sz[jj]);
    float dist = __fadd_rn(__fsub_rn(psq, __fmul_rn(2.0f, inner)), osq);
    if (dist < bd[10]) {
      int j = ch * CND + jj;
#pragma unroll
      for (int t = 10; t >= 0; --t) {
        float prev  = (t > 0) ? bd[t - 1] : -__builtin_inff();
        int   previ = (t > 0) ? bi[t - 1] : 0;
        bool mv = (dist < prev), here = (dist < bd[t]);
        bd[t] = mv ? prev  : (here ? dist : bd[t]);
        bi[t] = mv ? previ : (here ? j    : bi[t]);
      }
    }
  }
  size_t base = ((size_t)(b * NPTS + q) * CH + ch) * 11;
#pragma unroll
  for (int t = 0; t < 11; ++t) { pd[base + t] = bd[t]; pi[base + t] = bi[t]; }
}

// ---------------- chunked knn: phase 2 — lexicographic (d,idx) merge (R14 body) ------
template<int NPTS, int CH>
__global__ __launch_bounds__(256) void knn_merge_kernel(const float* __restrict__ pd,
                                                        const int* __restrict__ pi,
                                                        int* __restrict__ out) {
  const int gq = blockIdx.x * 256 + threadIdx.x;
  if (gq >= BB * NPTS) return;
  int head[CH];
#pragma unroll
  for (int c = 0; c < CH; ++c) head[c] = 0;
  for (int t = 0; t < 11; ++t) {
    float bestd = __builtin_inff(); int besti = 2147483647; int bc = 0;
#pragma unroll
    for (int c = 0; c < CH; ++c) {
      size_t base = ((size_t)gq * CH + c) * 11 + head[c];
      float d = pd[base]; int ix = pi[base];
      if (d < bestd || (d == bestd && ix < besti)) { bestd = d; besti = ix; bc = c; }
    }
    if (t > 0) out[(size_t)gq * KNN + (t - 1)] = besti;
    head[bc]++;
  }
}

// ---------------- chunked nearest: phase 1 (R14 body) ----------------
template<int NSRC, int CH>
__global__ __launch_bounds__(256) void nearest_part_kernel(const float* __restrict__ tgt,
                                                           const float* __restrict__ src,
                                                           float* __restrict__ pd,
                                                           int* __restrict__ pi) {
  constexpr int CND = NSRC / CH;
  __shared__ float sx[CND], sy[CND], sz[CND];
  const int bpb = V0 / 256;
  const int b = blockIdx.x / bpb;
  const int q = (blockIdx.x % bpb) * 256 + threadIdx.x;
  const int ch = blockIdx.y;
  const float* sb = src + (size_t)b * NSRC * 3;
  for (int i = threadIdx.x; i < CND; i += 256) {
    int j = ch * CND + i;
    sx[i] = sb[3 * j]; sy[i] = sb[3 * j + 1]; sz[i] = sb[3 * j + 2];
  }
  __syncthreads();
  const float* tp = tgt + ((size_t)b * V0 + q) * 3;
  const float px = tp[0], py = tp[1], pz = tp[2];
  float best = __builtin_inff(); int bidx = 0;
  for (int jj = 0; jj < CND; ++jj) {
    float inner = np_inner3(px, py, pz, sx[jj], sy[jj], sz[jj]);
    float osq = np_sq3(sx[jj], sy[jj], sz[jj]);
    float d = __fsub_rn(osq, __fmul_rn(2.0f, inner));
    if (d < best) { best = d; bidx = ch * CND + jj; }
  }
  size_t base = (size_t)(b * V0 + q) * CH + ch;
  pd[base] = best; pi[base] = bidx;
}

template<int CH>
__global__ __launch_bounds__(256) void nearest_merge_kernel(const float* __restrict__ pd,
                                                            const int* __restrict__ pi,
                                                            int* __restrict__ out) {
  const int gq = blockIdx.x * 256 + threadIdx.x;
  if (gq >= BB * V0) return;
  float bestd = __builtin_inff(); int besti = 2147483647;
#pragma unroll
  for (int c = 0; c < CH; ++c) {
    float d = pd[(size_t)gq * CH + c]; int ix = pi[(size_t)gq * CH + c];
    if (d < bestd || (d == bestd && ix < besti)) { bestd = d; besti = ix; }
  }
  out[gq] = besti;
}

// ---------------- conv_surface (unchanged) ----------------
__global__ __launch_bounds__(256) void conv_surface_kernel(
    const float* __restrict__ verts, const int* __restrict__ knn,
    const float* __restrict__ ndir, float* __restrict__ fm0) {
  const int wave = threadIdx.x >> 6;
  const int lane = threadIdx.x & 63;
  const int gv = blockIdx.x * 4 + wave;
  const int b = gv >> 12;
  const int v = gv & 4095;
  const float* vb = verts + (size_t)(b * V0 + v) * 3;
  float px = vb[0], py = vb[1], pz = vb[2];
  const int* kn = knn + (size_t)(b * V0 + v) * KNN;
  float dnx[KNN], dny[KNN], dnz[KNN];
#pragma unroll
  for (int n = 0; n < KNN; ++n) {
    const float* nb = verts + (size_t)(b * V0 + kn[n]) * 3;
    float dx = nb[0] - px, dy = nb[1] - py, dz = nb[2] - pz;
    float nr = fmaxf(sqrtf((dx * dx + dy * dy) + dz * dz), 1e-12f);
    dnx[n] = dx / nr; dny[n] = dy / nr; dnz[n] = dz / nr;
  }
  const int M = 7 * 128;
#pragma unroll
  for (int cc = 0; cc < 2; ++cc) {
    int c = cc * 64 + lane;
    float acc = 0.0f;
#pragma unroll
    for (int s = 0; s < 7; ++s) {
      int m = s * 128 + c;
      float n0 = ndir[m], n1 = ndir[M + m], n2 = ndir[2 * M + m];
      float mx = -__builtin_inff();
#pragma unroll
      for (int n = 0; n < KNN; ++n) {
        float t = (dnx[n] * n0 + dny[n] * n1) + dnz[n] * n2;
        mx = fmaxf(mx, t);
      }
      acc += fmaxf(mx, 0.0f);
    }
    fm0[(size_t)(b * V0 + v) * 128 + c] = fmaxf(acc, 0.0f);
  }
}

// ---------------- conv_layer: VECTORIZED lane->K-consecutive-channels (R18 body) -----
template<int OC>
__global__ __launch_bounds__(256) void conv_layer_kernel(
    const float* __restrict__ verts, const int* __restrict__ knn,
    const float* __restrict__ ndir, const float* __restrict__ fout,
    float* __restrict__ out, int V, int gvbase) {
  constexpr int K = OC / 64;
  const int wave = threadIdx.x >> 6;
  const int lane = threadIdx.x & 63;
  const int gv = gvbase + blockIdx.x * 4 + wave;
  const int b = gv / V;
  const int v = gv - b * V;
  const float* vb = verts + (size_t)(b * V + v) * 3;
  float px = vb[0], py = vb[1], pz = vb[2];
  const int* kn = knn + (size_t)(b * V + v) * KNN;
  float dnx[KNN], dny[KNN], dnz[KNN];
  size_t fb[KNN];
#pragma unroll
  for (int n = 0; n < KNN; ++n) {
    int j = kn[n];
    const float* nb = verts + (size_t)(b * V + j) * 3;
    float dx = nb[0] - px, dy = nb[1] - py, dz = nb[2] - pz;
    float nr = fmaxf(sqrtf((dx * dx + dy * dy) + dz * dz), 1e-12f);
    dnx[n] = dx / nr; dny[n] = dy / nr; dnz[n] = dz / nr;
    fb[n] = ((size_t)(b * V + j - gvbase) * 8 + 1) * OC;
  }
  const int M = 7 * OC;
  const int c0 = lane * K;
  const float* frow = fout + (size_t)(gv - gvbase) * (8 * OC);
  float acc[K];
#pragma unroll
  for (int k = 0; k < K; ++k) acc[k] = frow[c0 + k];
#pragma unroll
  for (int s = 0; s < 7; ++s) {
    const int m0 = s * OC + c0;
    float n0[K], n1[K], n2[K], mx[K];
#pragma unroll
    for (int k = 0; k < K; ++k) {
      n0[k] = ndir[m0 + k]; n1[k] = ndir[M + m0 + k]; n2[k] = ndir[2 * M + m0 + k];
      mx[k] = -__builtin_inff();
    }
#pragma unroll
    for (int n = 0; n < KNN; ++n) {
      float f[K];
#pragma unroll
      for (int k = 0; k < K; ++k) f[k] = fout[fb[n] + m0 + k];
#pragma unroll
      for (int k = 0; k < K; ++k) {
        float t = fmaxf((dnx[n] * n0[k] + dny[n] * n1[k]) + dnz[n] * n2[k], 0.0f);
        mx[k] = fmaxf(mx[k], t * f[k]);
      }
    }
#pragma unroll
    for (int k = 0; k < K; ++k) acc[k] += mx[k];
  }
  float* orow = out + (size_t)(b * V + v) * OC + c0;
#pragma unroll
  for (int k = 0; k < K; ++k) orow[k] = acc[k];
}

// ---------------- f32 GEMM with bias ----------------
__global__ __launch_bounds__(256) void gemm_bias_kernel(
    const float* __restrict__ A, const float* __restrict__ W,
    const float* __restrict__ bias, float* __restrict__ C,
    int M, int N, int K) {
  __shared__ float As[16][132];
  __shared__ float Bs[16][132];
  const int bn = blockIdx.x, bm = blockIdx.y;
  const int row0 = bm * 128, col0 = bn * 128;
  const int tid = threadIdx.x;
  const int tx = tid & 15, ty = tid >> 4;
  float acc[8][8];
#pragma unroll
  for (int i = 0; i < 8; ++i)
#pragma unroll
    for (int j = 0; j < 8; ++j) acc[i][j] = 0.0f;
  for (int k0 = 0; k0 < K; k0 += 16) {
    for (int t = tid; t < 512; t += 256) {
      int m = t >> 2, kq = (t & 3) << 2;
      float4 a = *reinterpret_cast<const float4*>(&A[(size_t)(row0 + m) * K + k0 + kq]);
      As[kq + 0][m] = a.x; As[kq + 1][m] = a.y; As[kq + 2][m] = a.z; As[kq + 3][m] = a.w;
    }
    for (int t = tid; t < 512; t += 256) {
      int k = t >> 5, nq = (t & 31) << 2;
      *reinterpret_cast<float4*>(&Bs[k][nq]) =
          *reinterpret_cast<const float4*>(&W[(size_t)(k0 + k) * N + col0 + nq]);
    }
    __syncthreads();
#pragma unroll
    for (int k = 0; k < 16; ++k) {
      float a[8], bb[8];
#pragma unroll
      for (int i = 0; i < 8; ++i) a[i] = As[k][ty * 8 + i];
#pragma unroll
      for (int j = 0; j < 8; ++j) bb[j] = Bs[k][tx * 8 + j];
#pragma unroll
      for (int i = 0; i < 8; ++i)
#pragma unroll
        for (int j = 0; j < 8; ++j)
          acc[i][j] = fmaf(a[i], bb[j], acc[i][j]);
    }
    __syncthreads();
  }
#pragma unroll
  for (int i = 0; i < 8; ++i) {
    const int r = row0 + ty * 8 + i;
#pragma unroll
    for (int j = 0; j < 8; ++j) {
      const int c = col0 + tx * 8 + j;
      C[(size_t)r * N + c] = acc[i][j] + bias[c];
    }
  }
}

// ---------------- batchnorm ----------------
template<int C>
__global__ __launch_bounds__(256) void bn_part_kernel(const float* __restrict__ x, int rows, int nchunks,
                                                      double* __restrict__ psum, double* __restrict__ psqs) {
  const int cg = blockIdx.x, chunk = blockIdx.y;
  const int lane = threadIdx.x & 63, sg = threadIdx.x >> 6;
  const int c = cg * 64 + lane;
  const int rp = rows / nchunks;
  const int r0 = chunk * rp;
  double s = 0.0, q = 0.0;
  for (int r = r0 + sg; r < r0 + rp; r += 4) {
    float v = x[(size_t)r * C + c];
    s += (double)v; q += (double)v * (double)v;
  }
  __shared__ double sh[8][64];
  sh[sg][lane] = s; sh[4 + sg][lane] = q;
  __syncthreads();
  if (sg == 0) {
    double S = ((sh[0][lane] + sh[1][lane]) + sh[2][lane]) + sh[3][lane];
    double Q = ((sh[4][lane] + sh[5][lane]) + sh[6][lane]) + sh[7][lane];
    psum[chunk * C + c] = S;
    psqs[chunk * C + c] = Q;
  }
}

__global__ void bn_fin_kernel(const double* __restrict__ psum, const double* __restrict__ psqs,
                              int nchunks, int C, int rows,
                              const float* __restrict__ gamma, const float* __restrict__ beta,
                              float* __restrict__ scale, float* __restrict__ shift) {
  const int c = blockIdx.x * 64 + threadIdx.x;
  if (c >= C) return;
  double S = 0.0, Q = 0.0;
  for (int k = 0; k < nchunks; ++k) { S += psum[k * C + c]; Q += psqs[k * C + c]; }
  double mean = S / rows;
  double var = Q / rows - mean * mean;
  float kk = (float)(1.0 / sqrt(var + 1e-5));
  float sc = kk * gamma[c];
  scale[c] = sc;
  shift[c] = beta[c] - (float)mean * sc;
}

template<int C>
__global__ __launch_bounds__(256) void bn_apply_kernel(float* __restrict__ x,
                                                       const float* __restrict__ scale,
                                                       const float* __restrict__ shift, int total) {
  int i = blockIdx.x * 256 + threadIdx.x;
  const int stride = gridDim.x * 256;
  for (; i < total; i += stride) {
    const int c = i & (C - 1);
    x[i] = fmaxf(x[i] * scale[c] + shift[c], 0.0f);
  }
}

// ---------------- pool ----------------
template<int C>
__global__ void pool_kernel(const float* __restrict__ fm, const float* __restrict__ verts,
                            const int* __restrict__ knn, const int* __restrict__ sample,
                            float* __restrict__ fp, float* __restrict__ vp, int Vin, int Vout) {
  const int bj = blockIdx.x;
  const int b = bj / Vout;
  const int j = bj - b * Vout;
  const int sv = sample[j];
  const int* kn = knn + (size_t)(b * Vin + sv) * KNN;
  const int t = threadIdx.x;
  float m = -__builtin_inff();
#pragma unroll
  for (int n = 0; n < 4; ++n)
    m = fmaxf(m, fm[(size_t)(b * Vin + kn[n]) * C + t]);
  fp[(size_t)(b * Vout + j) * C + t] = m;
  if (t < 3) vp[(size_t)(b * Vout + j) * 3 + t] = verts[(size_t)(b * Vin + sv) * 3 + t];
}

// ---------------- final concat ----------------
__global__ __launch_bounds__(256) void concat_kernel(
    const float* __restrict__ fm0, const float* __restrict__ fm1,
    const float* __restrict__ fm2, const float* __restrict__ fm3,
    const float* __restrict__ fm4, const int* __restrict__ n1,
    const int* __restrict__ n2, float* __restrict__ out) {
  const int bv = blockIdx.x;
  const int b = bv >> 12;
  const int t = threadIdx.x;
  float* orow = out + (size_t)bv * 1280;
  const int i1 = n1[bv], i2 = n2[bv];
  const float* r0 = fm0 + (size_t)bv * 128;
  const float* r1 = fm1 + (size_t)bv * 128;
  const float* r2 = fm2 + (size_t)(b * V1 + i1) * 256;
  const float* r3 = fm3 + (size_t)(b * V1 + i1) * 256;
  const float* r4 = fm4 + (size_t)(b * V2 + i2) * 512;
  orow[t] = (t < 128) ? r0[t] : r1[t - 128];
  orow[256 + t] = r2[t];
  orow[512 + t] = r3[t];
  orow[768 + t] = r4[t];
  orow[1024 + t] = r4[256 + t];
}

// ---------------- launcher ----------------
extern "C" void kernel_launch(void* const* d_in, const int* in_sizes, int n_in,
                              void* d_out, int out_size, void* d_ws, size_t ws_size,
                              hipStream_t stream) {
  const float* verts = (const float*)d_in[0];
  const float* dir0 = (const float*)d_in[1];
  const float* w1  = (const float*)d_in[2];
  const float* b1  = (const float*)d_in[3];
  const float* dir1 = (const float*)d_in[4];
  const float* g1  = (const float*)d_in[5];
  const float* be1 = (const float*)d_in[6];
  const float* w2  = (const float*)d_in[7];
  const float* b2  = (const float*)d_in[8];
  const float* dir2 = (const float*)d_in[9];
  const float* g2  = (const float*)d_in[10];
  const float* be2 = (const float*)d_in[11];
  const float* w3  = (const float*)d_in[12];
  const float* b3  = (const float*)d_in[13];
  const float* dir3 = (const float*)d_in[14];
  const float* g3  = (const float*)d_in[15];
  const float* be3 = (const float*)d_in[16];
  const float* w4  = (const float*)d_in[17];
  const float* b4  = (const float*)d_in[18];
  const float* dir4 = (const float*)d_in[19];
  float* out = (float*)d_out;
  (void)in_sizes; (void)n_in;

  char* base = (char*)d_ws;
  size_t off = 0;
  auto alloc = [&](size_t bytes) -> char* {
    char* p = base + off;
    off += (bytes + 1023) & ~(size_t)1023;
    return p;
  };
  float* ndir0 = (float*)alloc(3 * 896 * 4);
  float* ndir1 = (float*)alloc(3 * 896 * 4);
  float* ndir2 = (float*)alloc(3 * 1792 * 4);
  float* ndir3 = (float*)alloc(3 * 1792 * 4);
  float* ndir4 = (float*)alloc(3 * 3584 * 4);
  int* knn0 = (int*)alloc((size_t)BB * V0 * KNN * 4);
  int* knn1 = (int*)alloc((size_t)BB * V1 * KNN * 4);
  int* knn2 = (int*)alloc((size_t)BB * V2 * KNN * 4);
  int* smp1 = (int*)alloc(V1 * 4);
  int* smp2 = (int*)alloc(V2 * 4);
  int* n1   = (int*)alloc((size_t)BB * V0 * 4);
  int* n2   = (int*)alloc((size_t)BB * V0 * 4);
  // chunked knn/nearest scratch (sized for knn<4096,CH=32>)
  float* pd = (float*)alloc((size_t)BB * V0 * 32 * 11 * 4);
  int*   pi = (int*)  alloc((size_t)BB * V0 * 32 * 11 * 4);
  float* fm0 = (float*)alloc((size_t)BB * V0 * 128 * 4);
  float* fm1 = (float*)alloc((size_t)BB * V0 * 128 * 4);
  float* fm2 = (float*)alloc((size_t)BB * V1 * 256 * 4);
  float* fm3 = (float*)alloc((size_t)BB * V1 * 256 * 4);
  float* fm4 = (float*)alloc((size_t)BB * V2 * 512 * 4);
  float* vp1 = (float*)alloc((size_t)BB * V1 * 3 * 4);
  float* vp2 = (float*)alloc((size_t)BB * V2 * 3 * 4);
  float* fp1 = (float*)alloc((size_t)BB * V1 * 128 * 4);
  float* fp2 = (float*)alloc((size_t)BB * V2 * 256 * 4);
  double* psum = (double*)alloc(16 * 256 * 8);
  double* psqs = (double*)alloc(16 * 256 * 8);
  float* scale  = (float*)alloc(256 * 4);
  float* shiftv = (float*)alloc(256 * 4);
  // FULL fout: both batches (8192 x 1024 = 33.5 MB) — single-dispatch layer 1
  float* fout = (float*)alloc((size_t)BB * V0 * 1024 * 4);

  const int fill_grid = (out_size + 255) / 256;
  if (off > ws_size) {
    fill_kernel<<<fill_grid, 256, 0, stream>>>(out, 250.0f, out_size);
    return;
  }
  // strict RNG tripwire (host-only cost)
  if (!((fabs(nprng::first_double(42u) - 0.7739560485559633) < 2e-6) &&
        (fabs(nprng::first_double(12345u) - 0.22733602246716966) < 2e-6))) {
    fill_kernel<<<fill_grid, 256, 0, stream>>>(out, 160.0f, out_size);
    return;
  }

  // permutations (masked rejection — verified)
  int perm[V0];
  nprng::permutation(1u, V0, perm);
  IntPack256 pk;
  for (int ch = 0; ch < 4; ++ch) {
    for (int i = 0; i < 256; ++i) pk.v[i] = perm[ch * 256 + i];
    upload256_kernel<<<1, 256, 0, stream>>>(pk, smp1 + ch * 256);
  }
  nprng::permutation(2u, V1, perm);
  for (int i = 0; i < 256; ++i) pk.v[i] = perm[i];
  upload256_kernel<<<1, 256, 0, stream>>>(pk, smp2);

  norm_dirs_kernel<<<(896 + 255) / 256, 256, 0, stream>>>(dir0, ndir0, 896);
  norm_dirs_kernel<<<(896 + 255) / 256, 256, 0, stream>>>(dir1, ndir1, 896);
  norm_dirs_kernel<<<(1792 + 255) / 256, 256, 0, stream>>>(dir2, ndir2, 1792);
  norm_dirs_kernel<<<(1792 + 255) / 256, 256, 0, stream>>>(dir3, ndir3, 1792);
  norm_dirs_kernel<<<(3584 + 255) / 256, 256, 0, stream>>>(dir4, ndir4, 3584);

  // knn on full vertex set (CH 16 -> 32; bodies unchanged)
  knn_part_kernel<V0, 32><<<dim3(BB * V0 / 64, 32), 64, 0, stream>>>(verts, pd, pi);
  knn_merge_kernel<V0, 32><<<(BB * V0 + 255) / 256, 256, 0, stream>>>(pd, pi, knn0);

  conv_surface_kernel<<<BB * V0 / 4, 256, 0, stream>>>(verts, knn0, ndir0, fm0);

  // layer 1: single dispatch over both batches
  gemm_bias_kernel<<<dim3(8, 64), 256, 0, stream>>>(fm0, w1, b1, fout, BB * V0, 1024, 128);
  conv_layer_kernel<128><<<BB * V0 / 4, 256, 0, stream>>>(verts, knn0, ndir1, fout, fm1, V0, 0);

  bn_part_kernel<128><<<dim3(2, 16), 256, 0, stream>>>(fm1, BB * V0, 16, psum, psqs);
  bn_fin_kernel<<<2, 64, 0, stream>>>(psum, psqs, 16, 128, BB * V0, g1, be1, scale, shiftv);
  bn_apply_kernel<128><<<1024, 256, 0, stream>>>(fm1, scale, shiftv, BB * V0 * 128);

  pool_kernel<128><<<BB * V1, 128, 0, stream>>>(fm1, verts, knn0, smp1, fp1, vp1, V0, V1);
  knn_part_kernel<V1, 16><<<dim3(BB * V1 / 64, 16), 64, 0, stream>>>(vp1, pd, pi);
  knn_merge_kernel<V1, 16><<<(BB * V1 + 255) / 256, 256, 0, stream>>>(pd, pi, knn1);

  gemm_bias_kernel<<<dim3(16, 16), 256, 0, stream>>>(fp1, w2, b2, fout, BB * V1, 2048, 128);
  conv_layer_kernel<256><<<BB * V1 / 4, 256, 0, stream>>>(vp1, knn1, ndir2, fout, fm2, V1, 0);
  bn_part_kernel<256><<<dim3(4, 16), 256, 0, stream>>>(fm2, BB * V1, 16, psum, psqs);
  bn_fin_kernel<<<4, 64, 0, stream>>>(psum, psqs, 16, 256, BB * V1, g2, be2, scale, shiftv);
  bn_apply_kernel<256><<<1024, 256, 0, stream>>>(fm2, scale, shiftv, BB * V1 * 256);

  gemm_bias_kernel<<<dim3(16, 16), 256, 0, stream>>>(fm2, w3, b3, fout, BB * V1, 2048, 256);
  conv_layer_kernel<256><<<BB * V1 / 4, 256, 0, stream>>>(vp1, knn1, ndir3, fout, fm3, V1, 0);
  bn_part_kernel<256><<<dim3(4, 16), 256, 0, stream>>>(fm3, BB * V1, 16, psum, psqs);
  bn_fin_kernel<<<4, 64, 0, stream>>>(psum, psqs, 16, 256, BB * V1, g3, be3, scale, shiftv);
  bn_apply_kernel<256><<<1024, 256, 0, stream>>>(fm3, scale, shiftv, BB * V1 * 256);

  pool_kernel<256><<<BB * V2, 256, 0, stream>>>(fm3, vp1, knn1, smp2, fp2, vp2, V1, V2);
  knn_part_kernel<V2, 4><<<dim3(BB * V2 / 64, 4), 64, 0, stream>>>(vp2, pd, pi);
  knn_merge_kernel<V2, 4><<<(BB * V2 + 255) / 256, 256, 0, stream>>>(pd, pi, knn2);

  gemm_bias_kernel<<<dim3(32, 4), 256, 0, stream>>>(fp2, w4, b4, fout, BB * V2, 4096, 256);
  conv_layer_kernel<512><<<BB * V2 / 4, 256, 0, stream>>>(vp2, knn2, ndir4, fout, fm4, V2, 0);

  // chunked nearest-index (R14 bodies)
  nearest_part_kernel<V1, 8><<<dim3(BB * (V0 / 256), 8), 256, 0, stream>>>(verts, vp1, pd, pi);
  nearest_merge_kernel<8><<<(BB * V0 + 255) / 256, 256, 0, stream>>>(pd, pi, n1);
  nearest_part_kernel<V2, 4><<<dim3(BB * (V0 / 256), 4), 256, 0, stream>>>(verts, vp2, pd, pi);
  nearest_merge_kernel<4><<<(BB * V0 + 255) / 256, 256, 0, stream>>>(pd, pi, n2);

  concat_kernel<<<BB * V0, 256, 0, stream>>>(fm0, fm1, fm2, fm3, fm4, n1, n2, out);
}

// Round 20
// 631.766 us; speedup vs baseline: 1.0784x; 1.0784x over previous
//
#include <hip/hip_runtime.h>
#include <stdint.h>
#include <math.h>

// ---------------- problem constants ----------------
constexpr int BB = 2;
constexpr int V0 = 4096;
constexpr int V1 = 1024;
constexpr int V2 = 256;
constexpr int KNN = 10;

// ---------------- host-side NumPy RNG (sub-mix + masked rejection; VERIFIED R13) ------
namespace nprng {

typedef unsigned __int128 u128;
struct PCG { u128 state, inc; uint64_t buf; bool has32; };
static const u128 PCG_MUL = (((u128)0x2360ED051FC65DA4ULL) << 64) | 0x4385DF649FCCF645ULL;

static void pcg_init(uint32_t seed, PCG& g) {
  uint32_t hc = 0x43b0d7e5u;                    // INIT_A
  auto hashm = [&](uint32_t v, uint32_t mult) -> uint32_t {
    v ^= hc; hc *= mult; v *= hc; v ^= v >> 16; return v;
  };
  auto mixf = [](uint32_t x, uint32_t y) -> uint32_t {
    uint32_t r = (uint32_t)(x * 0xca01f9ddu - y * 0x4973f715u);  // SUBTRACTION
    r ^= r >> 16; return r;
  };
  uint32_t pool[4];
  pool[0] = hashm(seed, 0x931e8875u);
  for (int i = 1; i < 4; ++i) pool[i] = hashm(0u, 0x931e8875u);
  for (int s = 0; s < 4; ++s)
    for (int d = 0; d < 4; ++d)
      if (s != d) pool[d] = mixf(pool[d], hashm(pool[s], 0x931e8875u));
  hc = 0x8b51f9ddu;                             // INIT_B
  uint32_t w[8];
  for (int i = 0; i < 8; ++i) w[i] = hashm(pool[i & 3], 0x58f38dedu);
  uint64_t q0 = ((uint64_t)w[1] << 32) | w[0];
  uint64_t q1 = ((uint64_t)w[3] << 32) | w[2];
  uint64_t q2 = ((uint64_t)w[5] << 32) | w[4];
  uint64_t q3 = ((uint64_t)w[7] << 32) | w[6];
  u128 initstate = (((u128)q0) << 64) | q1;
  u128 initseq   = (((u128)q2) << 64) | q3;
  g.inc = (initseq << 1) | 1;
  g.state = g.inc;
  g.state += initstate;
  g.state = g.state * PCG_MUL + g.inc;
  g.has32 = false; g.buf = 0;
}

static uint64_t pcg_next64(PCG& g) {
  g.state = g.state * PCG_MUL + g.inc;
  uint64_t hi = (uint64_t)(g.state >> 64), lo = (uint64_t)g.state;
  unsigned r = (unsigned)(hi >> 58);
  uint64_t x = hi ^ lo;
  return (x >> r) | (x << ((64u - r) & 63u));
}

static uint32_t pcg_next32(PCG& g) {
  if (g.has32) { g.has32 = false; return (uint32_t)g.buf; }
  uint64_t n = pcg_next64(g);
  g.has32 = true; g.buf = n >> 32;
  return (uint32_t)n;                            // low 32 first
}

static uint32_t masked32(PCG& g, uint32_t rng) { // numpy random_interval
  uint32_t mask = rng;
  mask |= mask >> 1; mask |= mask >> 2; mask |= mask >> 4;
  mask |= mask >> 8; mask |= mask >> 16;
  uint32_t v;
  while ((v = (pcg_next32(g) & mask)) > rng) {}
  return v;
}

static void permutation(uint32_t seed, int n, int* out) {
  PCG g; pcg_init(seed, g);
  for (int i = 0; i < n; ++i) out[i] = i;
  for (int i = n - 1; i > 0; --i) {
    uint32_t j = masked32(g, (uint32_t)i);
    int t = out[j]; out[j] = out[i]; out[i] = t;
  }
}

static double first_double(uint32_t seed) {
  PCG g; pcg_init(seed, g);
  return (double)(pcg_next64(g) >> 11) * (1.0 / 9007199254740992.0);
}

} // namespace nprng

// ---------------- np-f32-exact distance pieces (no FMA contraction) ----------------
__device__ inline float np_sq3(float x, float y, float z) {
  return __fadd_rn(__fadd_rn(__fmul_rn(x, x), __fmul_rn(y, y)), __fmul_rn(z, z));
}
__device__ inline float np_inner3(float ax, float ay, float az, float bx, float by, float bz) {
  return __fadd_rn(__fadd_rn(__fmul_rn(ax, bx), __fmul_rn(ay, by)), __fmul_rn(az, bz));
}

// ---------------- ws-overflow guard ----------------
__global__ void fill_kernel(float* __restrict__ out, float v, int n) {
  int i = blockIdx.x * 256 + threadIdx.x;
  if (i < n) out[i] = v;
}

// ---------------- tiny upload kernel ----------------
struct IntPack256 { int v[256]; };
__global__ void upload256_kernel(IntPack256 p, int* __restrict__ dst) {
  dst[threadIdx.x] = p.v[threadIdx.x];
}

// ---------------- normalize direction columns ----------------
__global__ void norm_dirs_kernel(const float* __restrict__ d, float* __restrict__ nd, int M) {
  int m = blockIdx.x * 256 + threadIdx.x;
  if (m >= M) return;
  float a = d[m], b = d[M + m], c = d[2 * M + m];
  float n = sqrtf((a * a + b * b) + c * c);
  n = fmaxf(n, 1e-12f);
  nd[m] = a / n; nd[M + m] = b / n; nd[2 * M + m] = c / n;
}

// ---------------- chunked knn: phase 1 — per-chunk sorted top-11 (R14 body) ----------
template<int NPTS, int CH>
__global__ __launch_bounds__(64) void knn_part_kernel(const float* __restrict__ verts,
                                                      float* __restrict__ pd,
                                                      int* __restrict__ pi) {
  constexpr int CND = NPTS / CH;
  __shared__ float sx[CND], sy[CND], sz[CND];
  const int bpb = NPTS / 64;
  const int b = blockIdx.x / bpb;
  const int q = (blockIdx.x % bpb) * 64 + threadIdx.x;
  const int ch = blockIdx.y;
  const float* vb = verts + (size_t)b * NPTS * 3;
  for (int i = threadIdx.x; i < CND; i += 64) {
    int j = ch * CND + i;
    sx[i] = vb[3 * j]; sy[i] = vb[3 * j + 1]; sz[i] = vb[3 * j + 2];
  }
  __syncthreads();
  const float px = vb[3 * q], py = vb[3 * q + 1], pz = vb[3 * q + 2];
  const float psq = np_sq3(px, py, pz);
  float bd[11]; int bi[11];
#pragma unroll
  for (int t = 0; t < 11; ++t) { bd[t] = __builtin_inff(); bi[t] = 0; }
  for (int jj = 0; jj < CND; ++jj) {
    float inner = np_inner3(px, py, pz, sx[jj], sy[jj], sz[jj]);
    float osq = np_sq3(sx[jj], sy[jj], sz[jj]);
    float dist = __fadd_rn(__fsub_rn(psq, __fmul_rn(2.0f, inner)), osq);
    if (dist < bd[10]) {
      int j = ch * CND + jj;
#pragma unroll
      for (int t = 10; t >= 0; --t) {
        float prev  = (t > 0) ? bd[t - 1] : -__builtin_inff();
        int   previ = (t > 0) ? bi[t - 1] : 0;
        bool mv = (dist < prev), here = (dist < bd[t]);
        bd[t] = mv ? prev  : (here ? dist : bd[t]);
        bi[t] = mv ? previ : (here ? j    : bi[t]);
      }
    }
  }
  size_t base = ((size_t)(b * NPTS + q) * CH + ch) * 11;
#pragma unroll
  for (int t = 0; t < 11; ++t) { pd[base + t] = bd[t]; pi[base + t] = bi[t]; }
}

// ---------------- knn tree-merge stage A: merge CHSUB ADJACENT sorted lists ----------
// thread g handles lists [g*CHSUB, (g+1)*CHSUB) in the flattened (q*CHtot+c) space
// (groups tile queries contiguously). Output: full sorted 11-list at od[g*11..].
// Same lexicographic (d,idx) comparator as knn_merge; head<=10 during reads.
template<int CHSUB>
__global__ __launch_bounds__(256) void knn_mergeA_kernel(const float* __restrict__ pd,
                                                         const int* __restrict__ pi,
                                                         float* __restrict__ od,
                                                         int* __restrict__ oi,
                                                         int total) {
  const int g = blockIdx.x * 256 + threadIdx.x;
  if (g >= total) return;
  const size_t ibase = (size_t)g * CHSUB * 11;
  int head[CHSUB];
#pragma unroll
  for (int c = 0; c < CHSUB; ++c) head[c] = 0;
  for (int t = 0; t < 11; ++t) {
    float bestd = __builtin_inff(); int besti = 2147483647; int bc = 0;
#pragma unroll
    for (int c = 0; c < CHSUB; ++c) {
      size_t p = ibase + c * 11 + head[c];
      float d = pd[p]; int ix = pi[p];
      if (d < bestd || (d == bestd && ix < besti)) { bestd = d; besti = ix; bc = c; }
    }
    od[(size_t)g * 11 + t] = bestd;
    oi[(size_t)g * 11 + t] = besti;
    head[bc]++;
  }
}

// ---------------- chunked knn: final merge — lexicographic (d,idx), drop self --------
template<int NPTS, int CH>
__global__ __launch_bounds__(256) void knn_merge_kernel(const float* __restrict__ pd,
                                                        const int* __restrict__ pi,
                                                        int* __restrict__ out) {
  const int gq = blockIdx.x * 256 + threadIdx.x;
  if (gq >= BB * NPTS) return;
  int head[CH];
#pragma unroll
  for (int c = 0; c < CH; ++c) head[c] = 0;
  for (int t = 0; t < 11; ++t) {
    float bestd = __builtin_inff(); int besti = 2147483647; int bc = 0;
#pragma unroll
    for (int c = 0; c < CH; ++c) {
      size_t base = ((size_t)gq * CH + c) * 11 + head[c];
      float d = pd[base]; int ix = pi[base];
      if (d < bestd || (d == bestd && ix < besti)) { bestd = d; besti = ix; bc = c; }
    }
    if (t > 0) out[(size_t)gq * KNN + (t - 1)] = besti;
    head[bc]++;
  }
}

// ---------------- chunked nearest: phase 1 (R14 body) ----------------
template<int NSRC, int CH>
__global__ __launch_bounds__(256) void nearest_part_kernel(const float* __restrict__ tgt,
                                                           const float* __restrict__ src,
                                                           float* __restrict__ pd,
                                                           int* __restrict__ pi) {
  constexpr int CND = NSRC / CH;
  __shared__ float sx[CND], sy[CND], sz[CND];
  const int bpb = V0 / 256;
  const int b = blockIdx.x / bpb;
  const int q = (blockIdx.x % bpb) * 256 + threadIdx.x;
  const int ch = blockIdx.y;
  const float* sb = src + (size_t)b * NSRC * 3;
  for (int i = threadIdx.x; i < CND; i += 256) {
    int j = ch * CND + i;
    sx[i] = sb[3 * j]; sy[i] = sb[3 * j + 1]; sz[i] = sb[3 * j + 2];
  }
  __syncthreads();
  const float* tp = tgt + ((size_t)b * V0 + q) * 3;
  const float px = tp[0], py = tp[1], pz = tp[2];
  float best = __builtin_inff(); int bidx = 0;
  for (int jj = 0; jj < CND; ++jj) {
    float inner = np_inner3(px, py, pz, sx[jj], sy[jj], sz[jj]);
    float osq = np_sq3(sx[jj], sy[jj], sz[jj]);
    float d = __fsub_rn(osq, __fmul_rn(2.0f, inner));
    if (d < best) { best = d; bidx = ch * CND + jj; }
  }
  size_t base = (size_t)(b * V0 + q) * CH + ch;
  pd[base] = best; pi[base] = bidx;
}

template<int CH>
__global__ __launch_bounds__(256) void nearest_merge_kernel(const float* __restrict__ pd,
                                                            const int* __restrict__ pi,
                                                            int* __restrict__ out) {
  const int gq = blockIdx.x * 256 + threadIdx.x;
  if (gq >= BB * V0) return;
  float bestd = __builtin_inff(); int besti = 2147483647;
#pragma unroll
  for (int c = 0; c < CH; ++c) {
    float d = pd[(size_t)gq * CH + c]; int ix = pi[(size_t)gq * CH + c];
    if (d < bestd || (d == bestd && ix < besti)) { bestd = d; besti = ix; }
  }
  out[gq] = besti;
}

// ---------------- conv_surface (unchanged) ----------------
__global__ __launch_bounds__(256) void conv_surface_kernel(
    const float* __restrict__ verts, const int* __restrict__ knn,
    const float* __restrict__ ndir, float* __restrict__ fm0) {
  const int wave = threadIdx.x >> 6;
  const int lane = threadIdx.x & 63;
  const int gv = blockIdx.x * 4 + wave;
  const int b = gv >> 12;
  const int v = gv & 4095;
  const float* vb = verts + (size_t)(b * V0 + v) * 3;
  float px = vb[0], py = vb[1], pz = vb[2];
  const int* kn = knn + (size_t)(b * V0 + v) * KNN;
  float dnx[KNN], dny[KNN], dnz[KNN];
#pragma unroll
  for (int n = 0; n < KNN; ++n) {
    const float* nb = verts + (size_t)(b * V0 + kn[n]) * 3;
    float dx = nb[0] - px, dy = nb[1] - py, dz = nb[2] - pz;
    float nr = fmaxf(sqrtf((dx * dx + dy * dy) + dz * dz), 1e-12f);
    dnx[n] = dx / nr; dny[n] = dy / nr; dnz[n] = dz / nr;
  }
  const int M = 7 * 128;
#pragma unroll
  for (int cc = 0; cc < 2; ++cc) {
    int c = cc * 64 + lane;
    float acc = 0.0f;
#pragma unroll
    for (int s = 0; s < 7; ++s) {
      int m = s * 128 + c;
      float n0 = ndir[m], n1 = ndir[M + m], n2 = ndir[2 * M + m];
      float mx = -__builtin_inff();
#pragma unroll
      for (int n = 0; n < KNN; ++n) {
        float t = (dnx[n] * n0 + dny[n] * n1) + dnz[n] * n2;
        mx = fmaxf(mx, t);
      }
      acc += fmaxf(mx, 0.0f);
    }
    fm0[(size_t)(b * V0 + v) * 128 + c] = fmaxf(acc, 0.0f);
  }
}

// ---------------- conv_layer: VECTORIZED lane->K-consecutive-channels (R18 body) -----
template<int OC>
__global__ __launch_bounds__(256) void conv_layer_kernel(
    const float* __restrict__ verts, const int* __restrict__ knn,
    const float* __restrict__ ndir, const float* __restrict__ fout,
    float* __restrict__ out, int V, int gvbase) {
  constexpr int K = OC / 64;
  const int wave = threadIdx.x >> 6;
  const int lane = threadIdx.x & 63;
  const int gv = gvbase + blockIdx.x * 4 + wave;
  const int b = gv / V;
  const int v = gv - b * V;
  const float* vb = verts + (size_t)(b * V + v) * 3;
  float px = vb[0], py = vb[1], pz = vb[2];
  const int* kn = knn + (size_t)(b * V + v) * KNN;
  float dnx[KNN], dny[KNN], dnz[KNN];
  size_t fb[KNN];
#pragma unroll
  for (int n = 0; n < KNN; ++n) {
    int j = kn[n];
    const float* nb = verts + (size_t)(b * V + j) * 3;
    float dx = nb[0] - px, dy = nb[1] - py, dz = nb[2] - pz;
    float nr = fmaxf(sqrtf((dx * dx + dy * dy) + dz * dz), 1e-12f);
    dnx[n] = dx / nr; dny[n] = dy / nr; dnz[n] = dz / nr;
    fb[n] = ((size_t)(b * V + j - gvbase) * 8 + 1) * OC;
  }
  const int M = 7 * OC;
  const int c0 = lane * K;
  const float* frow = fout + (size_t)(gv - gvbase) * (8 * OC);
  float acc[K];
#pragma unroll
  for (int k = 0; k < K; ++k) acc[k] = frow[c0 + k];
#pragma unroll
  for (int s = 0; s < 7; ++s) {
    const int m0 = s * OC + c0;
    float n0[K], n1[K], n2[K], mx[K];
#pragma unroll
    for (int k = 0; k < K; ++k) {
      n0[k] = ndir[m0 + k]; n1[k] = ndir[M + m0 + k]; n2[k] = ndir[2 * M + m0 + k];
      mx[k] = -__builtin_inff();
    }
#pragma unroll
    for (int n = 0; n < KNN; ++n) {
      float f[K];
#pragma unroll
      for (int k = 0; k < K; ++k) f[k] = fout[fb[n] + m0 + k];
#pragma unroll
      for (int k = 0; k < K; ++k) {
        float t = fmaxf((dnx[n] * n0[k] + dny[n] * n1[k]) + dnz[n] * n2[k], 0.0f);
        mx[k] = fmaxf(mx[k], t * f[k]);
      }
    }
#pragma unroll
    for (int k = 0; k < K; ++k) acc[k] += mx[k];
  }
  float* orow = out + (size_t)(b * V + v) * OC + c0;
#pragma unroll
  for (int k = 0; k < K; ++k) orow[k] = acc[k];
}

// ---------------- f32 GEMM with bias ----------------
__global__ __launch_bounds__(256) void gemm_bias_kernel(
    const float* __restrict__ A, const float* __restrict__ W,
    const float* __restrict__ bias, float* __restrict__ C,
    int M, int N, int K) {
  __shared__ float As[16][132];
  __shared__ float Bs[16][132];
  const int bn = blockIdx.x, bm = blockIdx.y;
  const int row0 = bm * 128, col0 = bn * 128;
  const int tid = threadIdx.x;
  const int tx = tid & 15, ty = tid >> 4;
  float acc[8][8];
#pragma unroll
  for (int i = 0; i < 8; ++i)
#pragma unroll
    for (int j = 0; j < 8; ++j) acc[i][j] = 0.0f;
  for (int k0 = 0; k0 < K; k0 += 16) {
    for (int t = tid; t < 512; t += 256) {
      int m = t >> 2, kq = (t & 3) << 2;
      float4 a = *reinterpret_cast<const float4*>(&A[(size_t)(row0 + m) * K + k0 + kq]);
      As[kq + 0][m] = a.x; As[kq + 1][m] = a.y; As[kq + 2][m] = a.z; As[kq + 3][m] = a.w;
    }
    for (int t = tid; t < 512; t += 256) {
      int k = t >> 5, nq = (t & 31) << 2;
      *reinterpret_cast<float4*>(&Bs[k][nq]) =
          *reinterpret_cast<const float4*>(&W[(size_t)(k0 + k) * N + col0 + nq]);
    }
    __syncthreads();
#pragma unroll
    for (int k = 0; k < 16; ++k) {
      float a[8], bb[8];
#pragma unroll
      for (int i = 0; i < 8; ++i) a[i] = As[k][ty * 8 + i];
#pragma unroll
      for (int j = 0; j < 8; ++j) bb[j] = Bs[k][tx * 8 + j];
#pragma unroll
      for (int i = 0; i < 8; ++i)
#pragma unroll
        for (int j = 0; j < 8; ++j)
          acc[i][j] = fmaf(a[i], bb[j], acc[i][j]);
    }
    __syncthreads();
  }
#pragma unroll
  for (int i = 0; i < 8; ++i) {
    const int r = row0 + ty * 8 + i;
#pragma unroll
    for (int j = 0; j < 8; ++j) {
      const int c = col0 + tx * 8 + j;
      C[(size_t)r * N + c] = acc[i][j] + bias[c];
    }
  }
}

// ---------------- batchnorm ----------------
template<int C>
__global__ __launch_bounds__(256) void bn_part_kernel(const float* __restrict__ x, int rows, int nchunks,
                                                      double* __restrict__ psum, double* __restrict__ psqs) {
  const int cg = blockIdx.x, chunk = blockIdx.y;
  const int lane = threadIdx.x & 63, sg = threadIdx.x >> 6;
  const int c = cg * 64 + lane;
  const int rp = rows / nchunks;
  const int r0 = chunk * rp;
  double s = 0.0, q = 0.0;
  for (int r = r0 + sg; r < r0 + rp; r += 4) {
    float v = x[(size_t)r * C + c];
    s += (double)v; q += (double)v * (double)v;
  }
  __shared__ double sh[8][64];
  sh[sg][lane] = s; sh[4 + sg][lane] = q;
  __syncthreads();
  if (sg == 0) {
    double S = ((sh[0][lane] + sh[1][lane]) + sh[2][lane]) + sh[3][lane];
    double Q = ((sh[4][lane] + sh[5][lane]) + sh[6][lane]) + sh[7][lane];
    psum[chunk * C + c] = S;
    psqs[chunk * C + c] = Q;
  }
}

__global__ void bn_fin_kernel(const double* __restrict__ psum, const double* __restrict__ psqs,
                              int nchunks, int C, int rows,
                              const float* __restrict__ gamma, const float* __restrict__ beta,
                              float* __restrict__ scale, float* __restrict__ shift) {
  const int c = blockIdx.x * 64 + threadIdx.x;
  if (c >= C) return;
  double S = 0.0, Q = 0.0;
  for (int k = 0; k < nchunks; ++k) { S += psum[k * C + c]; Q += psqs[k * C + c]; }
  double mean = S / rows;
  double var = Q / rows - mean * mean;
  float kk = (float)(1.0 / sqrt(var + 1e-5));
  float sc = kk * gamma[c];
  scale[c] = sc;
  shift[c] = beta[c] - (float)mean * sc;
}

template<int C>
__global__ __launch_bounds__(256) void bn_apply_kernel(float* __restrict__ x,
                                                       const float* __restrict__ scale,
                                                       const float* __restrict__ shift, int total) {
  int i = blockIdx.x * 256 + threadIdx.x;
  const int stride = gridDim.x * 256;
  for (; i < total; i += stride) {
    const int c = i & (C - 1);
    x[i] = fmaxf(x[i] * scale[c] + shift[c], 0.0f);
  }
}

// ---------------- pool ----------------
template<int C>
__global__ void pool_kernel(const float* __restrict__ fm, const float* __restrict__ verts,
                            const int* __restrict__ knn, const int* __restrict__ sample,
                            float* __restrict__ fp, float* __restrict__ vp, int Vin, int Vout) {
  const int bj = blockIdx.x;
  const int b = bj / Vout;
  const int j = bj - b * Vout;
  const int sv = sample[j];
  const int* kn = knn + (size_t)(b * Vin + sv) * KNN;
  const int t = threadIdx.x;
  float m = -__builtin_inff();
#pragma unroll
  for (int n = 0; n < 4; ++n)
    m = fmaxf(m, fm[(size_t)(b * Vin + kn[n]) * C + t]);
  fp[(size_t)(b * Vout + j) * C + t] = m;
  if (t < 3) vp[(size_t)(b * Vout + j) * 3 + t] = verts[(size_t)(b * Vin + sv) * 3 + t];
}

// ---------------- final concat ----------------
__global__ __launch_bounds__(256) void concat_kernel(
    const float* __restrict__ fm0, const float* __restrict__ fm1,
    const float* __restrict__ fm2, const float* __restrict__ fm3,
    const float* __restrict__ fm4, const int* __restrict__ n1,
    const int* __restrict__ n2, float* __restrict__ out) {
  const int bv = blockIdx.x;
  const int b = bv >> 12;
  const int t = threadIdx.x;
  float* orow = out + (size_t)bv * 1280;
  const int i1 = n1[bv], i2 = n2[bv];
  const float* r0 = fm0 + (size_t)bv * 128;
  const float* r1 = fm1 + (size_t)bv * 128;
  const float* r2 = fm2 + (size_t)(b * V1 + i1) * 256;
  const float* r3 = fm3 + (size_t)(b * V1 + i1) * 256;
  const float* r4 = fm4 + (size_t)(b * V2 + i2) * 512;
  orow[t] = (t < 128) ? r0[t] : r1[t - 128];
  orow[256 + t] = r2[t];
  orow[512 + t] = r3[t];
  orow[768 + t] = r4[t];
  orow[1024 + t] = r4[256 + t];
}

// ---------------- launcher ----------------
extern "C" void kernel_launch(void* const* d_in, const int* in_sizes, int n_in,
                              void* d_out, int out_size, void* d_ws, size_t ws_size,
                              hipStream_t stream) {
  const float* verts = (const float*)d_in[0];
  const float* dir0 = (const float*)d_in[1];
  const float* w1  = (const float*)d_in[2];
  const float* b1  = (const float*)d_in[3];
  const float* dir1 = (const float*)d_in[4];
  const float* g1  = (const float*)d_in[5];
  const float* be1 = (const float*)d_in[6];
  const float* w2  = (const float*)d_in[7];
  const float* b2  = (const float*)d_in[8];
  const float* dir2 = (const float*)d_in[9];
  const float* g2  = (const float*)d_in[10];
  const float* be2 = (const float*)d_in[11];
  const float* w3  = (const float*)d_in[12];
  const float* b3  = (const float*)d_in[13];
  const float* dir3 = (const float*)d_in[14];
  const float* g3  = (const float*)d_in[15];
  const float* be3 = (const float*)d_in[16];
  const float* w4  = (const float*)d_in[17];
  const float* b4  = (const float*)d_in[18];
  const float* dir4 = (const float*)d_in[19];
  float* out = (float*)d_out;
  (void)in_sizes; (void)n_in;

  char* base = (char*)d_ws;
  size_t off = 0;
  auto alloc = [&](size_t bytes) -> char* {
    char* p = base + off;
    off += (bytes + 1023) & ~(size_t)1023;
    return p;
  };
  float* ndir0 = (float*)alloc(3 * 896 * 4);
  float* ndir1 = (float*)alloc(3 * 896 * 4);
  float* ndir2 = (float*)alloc(3 * 1792 * 4);
  float* ndir3 = (float*)alloc(3 * 1792 * 4);
  float* ndir4 = (float*)alloc(3 * 3584 * 4);
  int* knn0 = (int*)alloc((size_t)BB * V0 * KNN * 4);
  int* knn1 = (int*)alloc((size_t)BB * V1 * KNN * 4);
  int* knn2 = (int*)alloc((size_t)BB * V2 * KNN * 4);
  int* smp1 = (int*)alloc(V1 * 4);
  int* smp2 = (int*)alloc(V2 * 4);
  int* n1   = (int*)alloc((size_t)BB * V0 * 4);
  int* n2   = (int*)alloc((size_t)BB * V0 * 4);
  // chunked knn/nearest scratch (sized for knn<4096,CH=32>) + tree-merge intermediates
  float* pd = (float*)alloc((size_t)BB * V0 * 32 * 11 * 4);
  int*   pi = (int*)  alloc((size_t)BB * V0 * 32 * 11 * 4);
  float* od = (float*)alloc((size_t)BB * V0 * 8 * 11 * 4);
  int*   oi = (int*)  alloc((size_t)BB * V0 * 8 * 11 * 4);
  float* fm0 = (float*)alloc((size_t)BB * V0 * 128 * 4);
  float* fm1 = (float*)alloc((size_t)BB * V0 * 128 * 4);
  float* fm2 = (float*)alloc((size_t)BB * V1 * 256 * 4);
  float* fm3 = (float*)alloc((size_t)BB * V1 * 256 * 4);
  float* fm4 = (float*)alloc((size_t)BB * V2 * 512 * 4);
  float* vp1 = (float*)alloc((size_t)BB * V1 * 3 * 4);
  float* vp2 = (float*)alloc((size_t)BB * V2 * 3 * 4);
  float* fp1 = (float*)alloc((size_t)BB * V1 * 128 * 4);
  float* fp2 = (float*)alloc((size_t)BB * V2 * 256 * 4);
  double* psum = (double*)alloc(16 * 256 * 8);
  double* psqs = (double*)alloc(16 * 256 * 8);
  float* scale  = (float*)alloc(256 * 4);
  float* shiftv = (float*)alloc(256 * 4);
  // FULL fout: both batches (8192 x 1024 = 33.5 MB) — single-dispatch layer 1
  float* fout = (float*)alloc((size_t)BB * V0 * 1024 * 4);

  const int fill_grid = (out_size + 255) / 256;
  if (off > ws_size) {
    fill_kernel<<<fill_grid, 256, 0, stream>>>(out, 250.0f, out_size);
    return;
  }
  // strict RNG tripwire (host-only cost)
  if (!((fabs(nprng::first_double(42u) - 0.7739560485559633) < 2e-6) &&
        (fabs(nprng::first_double(12345u) - 0.22733602246716966) < 2e-6))) {
    fill_kernel<<<fill_grid, 256, 0, stream>>>(out, 160.0f, out_size);
    return;
  }

  // permutations (masked rejection — verified)
  int perm[V0];
  nprng::permutation(1u, V0, perm);
  IntPack256 pk;
  for (int ch = 0; ch < 4; ++ch) {
    for (int i = 0; i < 256; ++i) pk.v[i] = perm[ch * 256 + i];
    upload256_kernel<<<1, 256, 0, stream>>>(pk, smp1 + ch * 256);
  }
  nprng::permutation(2u, V1, perm);
  for (int i = 0; i < 256; ++i) pk.v[i] = perm[i];
  upload256_kernel<<<1, 256, 0, stream>>>(pk, smp2);

  norm_dirs_kernel<<<(896 + 255) / 256, 256, 0, stream>>>(dir0, ndir0, 896);
  norm_dirs_kernel<<<(896 + 255) / 256, 256, 0, stream>>>(dir1, ndir1, 896);
  norm_dirs_kernel<<<(1792 + 255) / 256, 256, 0, stream>>>(dir2, ndir2, 1792);
  norm_dirs_kernel<<<(1792 + 255) / 256, 256, 0, stream>>>(dir3, ndir3, 1792);
  norm_dirs_kernel<<<(3584 + 255) / 256, 256, 0, stream>>>(dir4, ndir4, 3584);

  // knn on full vertex set: part CH=32 (verified R19) + two-stage tree merge
  knn_part_kernel<V0, 32><<<dim3(BB * V0 / 64, 32), 64, 0, stream>>>(verts, pd, pi);
  knn_mergeA_kernel<4><<<(BB * V0 * 8 + 255) / 256, 256, 0, stream>>>(pd, pi, od, oi, BB * V0 * 8);
  knn_merge_kernel<V0, 8><<<(BB * V0 + 255) / 256, 256, 0, stream>>>(od, oi, knn0);

  conv_surface_kernel<<<BB * V0 / 4, 256, 0, stream>>>(verts, knn0, ndir0, fm0);

  // layer 1: single dispatch over both batches
  gemm_bias_kernel<<<dim3(8, 64), 256, 0, stream>>>(fm0, w1, b1, fout, BB * V0, 1024, 128);
  conv_layer_kernel<128><<<BB * V0 / 4, 256, 0, stream>>>(verts, knn0, ndir1, fout, fm1, V0, 0);

  bn_part_kernel<128><<<dim3(2, 16), 256, 0, stream>>>(fm1, BB * V0, 16, psum, psqs);
  bn_fin_kernel<<<2, 64, 0, stream>>>(psum, psqs, 16, 128, BB * V0, g1, be1, scale, shiftv);
  bn_apply_kernel<128><<<1024, 256, 0, stream>>>(fm1, scale, shiftv, BB * V0 * 128);

  pool_kernel<128><<<BB * V1, 128, 0, stream>>>(fm1, verts, knn0, smp1, fp1, vp1, V0, V1);
  // knn V1: part CH=16 (verified R19) + two-stage tree merge
  knn_part_kernel<V1, 16><<<dim3(BB * V1 / 64, 16), 64, 0, stream>>>(vp1, pd, pi);
  knn_mergeA_kernel<4><<<(BB * V1 * 4 + 255) / 256, 256, 0, stream>>>(pd, pi, od, oi, BB * V1 * 4);
  knn_merge_kernel<V1, 4><<<(BB * V1 + 255) / 256, 256, 0, stream>>>(od, oi, knn1);

  gemm_bias_kernel<<<dim3(16, 16), 256, 0, stream>>>(fp1, w2, b2, fout, BB * V1, 2048, 128);
  conv_layer_kernel<256><<<BB * V1 / 4, 256, 0, stream>>>(vp1, knn1, ndir2, fout, fm2, V1, 0);
  bn_part_kernel<256><<<dim3(4, 16), 256, 0, stream>>>(fm2, BB * V1, 16, psum, psqs);
  bn_fin_kernel<<<4, 64, 0, stream>>>(psum, psqs, 16, 256, BB * V1, g2, be2, scale, shiftv);
  bn_apply_kernel<256><<<1024, 256, 0, stream>>>(fm2, scale, shiftv, BB * V1 * 256);

  gemm_bias_kernel<<<dim3(16, 16), 256, 0, stream>>>(fm2, w3, b3, fout, BB * V1, 2048, 256);
  conv_layer_kernel<256><<<BB * V1 / 4, 256, 0, stream>>>(vp1, knn1, ndir3, fout, fm3, V1, 0);
  bn_part_kernel<256><<<dim3(4, 16), 256, 0, stream>>>(fm3, BB * V1, 16, psum, psqs);
  bn_fin_kernel<<<4, 64, 0, stream>>>(psum, psqs, 16, 256, BB * V1, g3, be3, scale, shiftv);
  bn_apply_kernel<256><<<1024, 256, 0, stream>>>(fm3, scale, shiftv, BB * V1 * 256);

  pool_kernel<256><<<BB * V2, 256, 0, stream>>>(fm3, vp1, knn1, smp2, fp2, vp2, V1, V2);
  knn_part_kernel<V2, 4><<<dim3(BB * V2 / 64, 4), 64, 0, stream>>>(vp2, pd, pi);
  knn_merge_kernel<V2, 4><<<(BB * V2 + 255) / 256, 256, 0, stream>>>(pd, pi, knn2);

  gemm_bias_kernel<<<dim3(32, 4), 256, 0, stream>>>(fp2, w4, b4, fout, BB * V2, 4096, 256);
  conv_layer_kernel<512><<<BB * V2 / 4, 256, 0, stream>>>(vp2, knn2, ndir4, fout, fm4, V2, 0);

  // chunked nearest-index (unchanged)
  nearest_part_kernel<V1, 8><<<dim3(BB * (V0 / 256), 8), 256, 0, stream>>>(verts, vp1, pd, pi);
  nearest_merge_kernel<8><<<(BB * V0 + 255) / 256, 256, 0, stream>>>(pd, pi, n1);
  nearest_part_kernel<V2, 4><<<dim3(BB * (V0 / 256), 4), 256, 0, stream>>>(verts, vp2, pd, pi);
  nearest_merge_kernel<4><<<(BB * V0 + 255) / 256, 256, 0, stream>>>(pd, pi, n2);

  concat_kernel<<<BB * V0, 256, 0, stream>>>(fm0, fm1, fm2, fm3, fm4, n1, n2, out);
}